// Round 1
// baseline (944.581 us; speedup 1.0000x reference)
//
#include <hip/hip_runtime.h>
#include <hip/hip_bf16.h>

#define B_ 16
#define S_ 80
#define D_ 512
#define H_ 64
#define DI_ 2048
#define L_ 6
#define G4H 256            // 4*H
#define NROW (B_ * S_)     // 1280 rows = (b, s)
#define EPS_ 1e-6f

typedef __attribute__((ext_vector_type(8))) short short8;
typedef __attribute__((ext_vector_type(4))) float f32x4;

// ---------------- math helpers ----------------
__device__ __forceinline__ float sigmoidf_(float x) {
    return __fdividef(1.0f, 1.0f + __expf(-x));
}
__device__ __forceinline__ float tanh_(float x) {
    return __fdividef(2.0f, 1.0f + __expf(-2.0f * x)) - 1.0f;
}
__device__ __forceinline__ short f2bf(float f) {
    __hip_bfloat16 h = __float2bfloat16(f);   // RNE
    return *reinterpret_cast<short*>(&h);
}

// Barrier that waits only on LDS traffic (lgkmcnt), NOT on in-flight global loads.
__device__ __forceinline__ void lds_barrier() {
    __asm__ volatile("s_waitcnt lgkmcnt(0)\n\ts_barrier" ::: "memory");
}

// ---------------- fp32 -> bf16 weight conversion (once per launch) ----------------
__global__ __launch_bounds__(256)
void w2bf_kernel(const float* __restrict__ s, __hip_bfloat16* __restrict__ d, int n4) {
    int i = blockIdx.x * 256 + threadIdx.x;
    if (i < n4) {
        float4 v = reinterpret_cast<const float4*>(s)[i];
        short4 o;
        o.x = f2bf(v.x); o.y = f2bf(v.y); o.z = f2bf(v.z); o.w = f2bf(v.w);
        reinterpret_cast<short4*>(d)[i] = o;
    }
}

// ---------------- Whh -> per-lane bf16 A-fragment layout (once per launch) ----------------
// wfb[l][t16][kc][lane][j] = bf16( whh[l][16*t16 + (lane&15)][kc*32 + ((lane>>4)&3)*8 + j] )
// so the LSTM loads its 32 A-frags as 32 contiguous 1KB vector loads.
__global__ __launch_bounds__(256)
void whh_frag_kernel(const float* __restrict__ whh, __hip_bfloat16* __restrict__ wfb) {
    int idx = blockIdx.x * 256 + threadIdx.x;          // total L_*16*2*64*8 = 98304
    int j    = idx & 7;
    int lane = (idx >> 3) & 63;
    int kc   = (idx >> 9) & 1;
    int t16  = (idx >> 10) & 15;
    int l    = idx >> 14;
    int row = 16 * t16 + (lane & 15);
    int col = kc * 32 + ((lane >> 4) & 3) * 8 + j;
    wfb[idx] = __float2bfloat16(whh[((size_t)l * G4H + row) * H_ + col]);
}

// ---------------- LayerNorm: one block per row, shuffle reduce (2 barriers) ----------------
__global__ __launch_bounds__(256)
void ln_kernel(const float* __restrict__ x, const float* __restrict__ g,
               const float* __restrict__ b, __hip_bfloat16* __restrict__ out) {
    int row = blockIdx.x;
    int t = threadIdx.x;
    const float* xr = x + (size_t)row * D_;
    float v0 = xr[t], v1 = xr[t + 256];
    __shared__ float ws4[4], qs4[4];
    float s = v0 + v1;
    #pragma unroll
    for (int o = 32; o > 0; o >>= 1) s += __shfl_down(s, o);
    if ((t & 63) == 0) ws4[t >> 6] = s;
    __syncthreads();
    float m = (ws4[0] + ws4[1] + ws4[2] + ws4[3]) * (1.0f / (float)D_);
    float d0 = v0 - m, d1 = v1 - m;
    float q = d0 * d0 + d1 * d1;
    #pragma unroll
    for (int o = 32; o > 0; o >>= 1) q += __shfl_down(q, o);
    if ((t & 63) == 0) qs4[t >> 6] = q;
    __syncthreads();
    float rs = rsqrtf((qs4[0] + qs4[1] + qs4[2] + qs4[3]) * (1.0f / (float)D_) + EPS_);
    __hip_bfloat16* orow = out + (size_t)row * D_;
    orow[t]       = __float2bfloat16(d0 * rs * g[t]       + b[t]);
    orow[t + 256] = __float2bfloat16(d1 * rs * g[t + 256] + b[t + 256]);
}

// ---------------- bf16 MFMA GEMM: C[M,N] = A[M,K] @ W[N,K]^T (+bias)(+relu)(+res) -----------
// OUT_MODE: 0 = fp32 row-major, 1 = bf16 row-major,
//           2 = fp32 xg layout [s][gate][bp][u][b2]  (bp=b>>1, b2=b&1)
template<int WITH_BIAS, int WITH_RELU, int WITH_RES, int OUT_MODE>
__global__ __launch_bounds__(256)
void mfma_gemm(const __hip_bfloat16* __restrict__ A, const __hip_bfloat16* __restrict__ W,
               const float* __restrict__ bias, const float* __restrict__ res,
               void* __restrict__ C, int M, int N, int K) {
    const int LDT = 72;  // LDS row stride in shorts (144B rows, 16B-aligned)
    __shared__ short As[64 * LDT];
    __shared__ short Ws[64 * LDT];

    int tid  = threadIdx.x;
    int wave = tid >> 6, lane = tid & 63;
    int quad = lane >> 4, l16 = lane & 15;
    int m_off = (wave >> 1) * 32, n_off = (wave & 1) * 32;
    int m0 = blockIdx.y * 64, n0 = blockIdx.x * 64;

    int r = tid >> 2, c = tid & 3;           // staging: row 0..63, 16-elem chunk 0..3
    const short* Ag = reinterpret_cast<const short*>(A);
    const short* Wg = reinterpret_cast<const short*>(W);

    f32x4 acc00 = {0.f,0.f,0.f,0.f}, acc01 = acc00, acc10 = acc00, acc11 = acc00;

    short8 avA[2], avW[2];                   // staged tile in registers
    auto load_tile = [&](int k0) {
        const short* arow = &Ag[(size_t)(m0 + r) * K + k0 + c * 16];
        avA[0] = *reinterpret_cast<const short8*>(arow);
        avA[1] = *reinterpret_cast<const short8*>(arow + 8);
        const short* wrow = &Wg[(size_t)(n0 + r) * K + k0 + c * 16];
        avW[0] = *reinterpret_cast<const short8*>(wrow);
        avW[1] = *reinterpret_cast<const short8*>(wrow + 8);
    };

    load_tile(0);                            // prologue
    for (int k0 = 0; k0 < K; k0 += 64) {
        lds_barrier();                       // prev frag reads done; vmem stays in flight
        *reinterpret_cast<short8*>(&As[r * LDT + c * 16])     = avA[0];
        *reinterpret_cast<short8*>(&As[r * LDT + c * 16 + 8]) = avA[1];
        *reinterpret_cast<short8*>(&Ws[r * LDT + c * 16])     = avW[0];
        *reinterpret_cast<short8*>(&Ws[r * LDT + c * 16 + 8]) = avW[1];
        lds_barrier();
        if (k0 + 64 < K) load_tile(k0 + 64); // issue next loads; consumed next iteration

        #pragma unroll
        for (int kc = 0; kc < 2; kc++) {
            short8 a0 = *reinterpret_cast<const short8*>(&As[(m_off + l16) * LDT + kc * 32 + quad * 8]);
            short8 a1 = *reinterpret_cast<const short8*>(&As[(m_off + 16 + l16) * LDT + kc * 32 + quad * 8]);
            short8 b0 = *reinterpret_cast<const short8*>(&Ws[(n_off + l16) * LDT + kc * 32 + quad * 8]);
            short8 b1 = *reinterpret_cast<const short8*>(&Ws[(n_off + 16 + l16) * LDT + kc * 32 + quad * 8]);
            acc00 = __builtin_amdgcn_mfma_f32_16x16x32_bf16(a0, b0, acc00, 0, 0, 0);
            acc01 = __builtin_amdgcn_mfma_f32_16x16x32_bf16(a0, b1, acc01, 0, 0, 0);
            acc10 = __builtin_amdgcn_mfma_f32_16x16x32_bf16(a1, b0, acc10, 0, 0, 0);
            acc11 = __builtin_amdgcn_mfma_f32_16x16x32_bf16(a1, b1, acc11, 0, 0, 0);
        }
    }

    f32x4 accs[2][2] = {{acc00, acc01}, {acc10, acc11}};
    #pragma unroll
    for (int fi = 0; fi < 2; fi++) {
        #pragma unroll
        for (int fj = 0; fj < 2; fj++) {
            int coln = n0 + n_off + fj * 16 + l16;
            float bv = WITH_BIAS ? bias[coln] : 0.0f;
            #pragma unroll
            for (int rr = 0; rr < 4; rr++) {
                int rowm = m0 + m_off + fi * 16 + quad * 4 + rr;
                float v = accs[fi][fj][rr];
                if (WITH_BIAS) v += bv;
                if (WITH_RELU) v = fmaxf(v, 0.0f);
                if (WITH_RES)  v += res[(size_t)rowm * N + coln];
                if (OUT_MODE == 0) {
                    reinterpret_cast<float*>(C)[(size_t)rowm * N + coln] = v;
                } else if (OUT_MODE == 1) {
                    reinterpret_cast<__hip_bfloat16*>(C)[(size_t)rowm * N + coln] = __float2bfloat16(v);
                } else {
                    int b_ = rowm / S_;
                    int s_ = rowm - b_ * S_;
                    int gate = coln >> 6, u = coln & 63;
                    int bp = b_ >> 1, b2 = b_ & 1;
                    reinterpret_cast<float*>(C)[
                        (((size_t)s_ * 4 + gate) * 8 + bp) * 128 + (u << 1) + b2] = v;
                }
            }
        }
    }
}

// ---------------- MFMA LSTM v5: wave-private recurrences, NO barriers ----------------
// The recurrence is independent per (output position i, batch b). Each wave owns ONE
// (i, batch-pair): it computes all 256 gate pre-activations for its 2 sequences with
// 32 MFMAs (transposed orientation: D[gu][seq] = Whh x h^T, Whh held entirely in 128
// VGPRs of bf16 A-frags), redistributes the 8-lane-concentrated output through a
// wave-private LDS scratch so the nonlinearity runs at 2 states/lane, and round-trips
// h through a private 2-row LDS tile. No s_barrier anywhere; only same-wave lgkmcnt
// waits. Grid (80,2) x 256 = 640 independent waves. xg is consumed via 4 coalesced
// dwordx2 loads per step, register-prefetched 2 steps deep.
__global__ __launch_bounds__(256, 1)
void lstm_v5_kernel(const float* __restrict__ xg7,            // [S][4][8][64][2] fp32
                    const __hip_bfloat16* __restrict__ wfb,   // [16][2][64][8] bf16 (layer slice)
                    __hip_bfloat16* __restrict__ hlast) {     // [B, S, H]
    const int i    = blockIdx.x;                  // output position 0..79
    const int tid  = threadIdx.x;
    const int wave = tid >> 6, lane = tid & 63;
    const int quad = lane >> 4, l16 = lane & 15;
    const int bp   = blockIdx.y * 4 + wave;       // batch pair 0..7

    // wave-private LDS: h rows (only rows 0,1 live; rows 2..15 stay zero so MFMA
    // cols 2..15 compute harmless zeros) + ifgo scatter buffer
    __shared__ __attribute__((aligned(16))) short hsh[4][16][72];
    __shared__ __attribute__((aligned(16))) float gbf[4][64 * 2 * 4];

    {   // zero own h tile (h_0 = 0): 16*72 shorts = 576 dwords, 9 per lane
        int* hp = reinterpret_cast<int*>(&hsh[wave][0][0]);
        #pragma unroll
        for (int k = 0; k < 9; k++) hp[lane + 64 * k] = 0;
    }

    // Whh A-fragments: whole 256x64 in registers (32 x short8 = 128 VGPR)
    short8 wf[16][2];
    {
        const short* ws = reinterpret_cast<const short*>(wfb);
        #pragma unroll
        for (int t16 = 0; t16 < 16; t16++)
            #pragma unroll
            for (int kc = 0; kc < 2; kc++)
                wf[t16][kc] = *reinterpret_cast<const short8*>(
                    &ws[(((t16 * 2 + kc) * 64) + lane) * 8]);
    }

    char* gb = reinterpret_cast<char*>(&gbf[wave][0]);
    const int swr = ((lane >> 2) & 3) << 4;       // reader-side XOR swizzle (u = lane)

    float cst0 = 0.f, cst1 = 0.f, h0 = 0.f, h1 = 0.f;

    float2 xva[4], xvb[4];
    auto xload = [&](float2 (&xv)[4], int t) {
        int s = (t == i) ? (S_ - 1) : ((t == S_ - 1) ? i : t);   // janossy permutation
        const float* xb = xg7 + (size_t)s * 4096 + (size_t)bp * 128 + lane * 2;
        #pragma unroll
        for (int g = 0; g < 4; g++)
            xv[g] = *reinterpret_cast<const float2*>(xb + g * 1024);
    };
    xload(xva, 0);
    xload(xvb, 1);
    __asm__ volatile("s_waitcnt lgkmcnt(0)" ::: "memory");   // h zeros visible (same wave)

    const f32x4 zacc = {0.f, 0.f, 0.f, 0.f};

    auto step = [&](int t, float2 (&xc)[4]) {
        // B-frags from own h rows: B[k=quad*8+j][col=l16] = h[seq=l16][u=k]
        short8 bf0 = *reinterpret_cast<const short8*>(&hsh[wave][l16][quad * 8]);
        short8 bf1 = *reinterpret_cast<const short8*>(&hsh[wave][l16][32 + quad * 8]);

        // D[gu][seq] = Whh @ h^T : 16 M-tiles x K=64 (2 chained MFMAs each)
        f32x4 acc[16];
        #pragma unroll
        for (int t16 = 0; t16 < 16; t16++)
            acc[t16] = __builtin_amdgcn_mfma_f32_16x16x32_bf16(wf[t16][0], bf0, zacc, 0, 0, 0);
        #pragma unroll
        for (int t16 = 0; t16 < 16; t16++)
            acc[t16] = __builtin_amdgcn_mfma_f32_16x16x32_bf16(wf[t16][1], bf1, acc[t16], 0, 0, 0);

        // scatter ifgo per (u, seq) to private LDS (only cols 0,1 are real sequences).
        // gu = 16*t16 + 4*quad + r with t16 = 4*gate + mm  ->  u = 16*mm + 4*quad + r
        if (l16 < 2) {
            #pragma unroll
            for (int mm = 0; mm < 4; mm++)
                #pragma unroll
                for (int r = 0; r < 4; r++) {
                    int u = 16 * mm + 4 * quad + r;
                    f32x4 v = {acc[mm][r], acc[4 + mm][r], acc[8 + mm][r], acc[12 + mm][r]};
                    *reinterpret_cast<f32x4*>(gb + ((u * 32 + l16 * 16) ^ (quad << 4))) = v;
                }
        }
        __asm__ volatile("s_waitcnt lgkmcnt(0)" ::: "memory");

        // gather: lane owns u = lane, both seqs -> 2 states/lane
        f32x4 ga = *reinterpret_cast<const f32x4*>(gb + ((lane * 32)      ^ swr));
        f32x4 gc = *reinterpret_cast<const f32x4*>(gb + ((lane * 32 + 16) ^ swr));

        float i0 = ga[0] + xc[0].x, f0 = ga[1] + xc[1].x, g0 = ga[2] + xc[2].x, o0 = ga[3] + xc[3].x;
        float i1 = gc[0] + xc[0].y, f1 = gc[1] + xc[1].y, g1 = gc[2] + xc[2].y, o1 = gc[3] + xc[3].y;

        // prefetch xg for t+2 into the slot just consumed (in flight ~2 steps)
        if (t + 2 < S_) xload(xc, t + 2);

        cst0 = sigmoidf_(f0) * cst0 + sigmoidf_(i0) * tanh_(g0);
        cst1 = sigmoidf_(f1) * cst1 + sigmoidf_(i1) * tanh_(g1);
        h0 = sigmoidf_(o0) * tanh_(cst0);
        h1 = sigmoidf_(o1) * tanh_(cst1);

        hsh[wave][0][lane] = f2bf(h0);
        hsh[wave][1][lane] = f2bf(h1);
        __asm__ volatile("s_waitcnt lgkmcnt(0)" ::: "memory");
    };

    for (int t = 0; t < S_; t += 2) { step(t, xva); step(t + 1, xvb); }

    hlast[((size_t)(bp * 2 + 0) * S_ + i) * H_ + lane] = __float2bfloat16(h0);
    hlast[((size_t)(bp * 2 + 1) * S_ + i) * H_ + lane] = __float2bfloat16(h1);
}

// ---------------- final LN + projection to one logit per row ----------------
__global__ __launch_bounds__(256)
void final_kernel(const float* __restrict__ x, const float* __restrict__ g,
                  const float* __restrict__ b, const float* __restrict__ wprj,
                  float* __restrict__ out) {
    int row = blockIdx.x;
    int t = threadIdx.x;
    const float* xr = x + (size_t)row * D_;
    float v0 = xr[t], v1 = xr[t + 256];
    __shared__ float red[256];
    red[t] = v0 + v1;
    __syncthreads();
    for (int o = 128; o > 0; o >>= 1) { if (t < o) red[t] += red[t + o]; __syncthreads(); }
    float m = red[0] * (1.0f / (float)D_);
    __syncthreads();
    float d0 = v0 - m, d1 = v1 - m;
    red[t] = d0 * d0 + d1 * d1;
    __syncthreads();
    for (int o = 128; o > 0; o >>= 1) { if (t < o) red[t] += red[t + o]; __syncthreads(); }
    float rs = rsqrtf(red[0] * (1.0f / (float)D_) + EPS_);
    __syncthreads();
    float y0 = (d0 * rs * g[t] + b[t]) * wprj[t];
    float y1 = (d1 * rs * g[t + 256] + b[t + 256]) * wprj[t + 256];
    red[t] = y0 + y1;
    __syncthreads();
    for (int o = 128; o > 0; o >>= 1) { if (t < o) red[t] += red[t + o]; __syncthreads(); }
    if (t == 0) out[row] = red[0];
}

// ---------------- host ----------------
extern "C" void kernel_launch(void* const* d_in, const int* in_sizes, int n_in,
                              void* d_out, int out_size, void* d_ws, size_t ws_size,
                              hipStream_t stream) {
    const float* src   = (const float*)d_in[0];
    const float* ln1_g = (const float*)d_in[2];
    const float* ln1_b = (const float*)d_in[3];
    const float* wih   = (const float*)d_in[4];   // [L, 4H, D]
    const float* whh   = (const float*)d_in[5];   // [L, 4H, H]
    const float* wfc   = (const float*)d_in[6];   // [L, D, H]
    const float* ln2_g = (const float*)d_in[7];
    const float* ln2_b = (const float*)d_in[8];
    const float* w1    = (const float*)d_in[9];   // [L, DI, D]
    const float* b1    = (const float*)d_in[10];  // [L, DI]
    const float* w2    = (const float*)d_in[11];  // [L, D, DI]
    const float* b2    = (const float*)d_in[12];  // [L, D]
    const float* lnf_g = (const float*)d_in[13];
    const float* lnf_b = (const float*)d_in[14];
    const float* wprj  = (const float*)d_in[15];  // [1, D]
    float* out = (float*)d_out;

    char* ws = (char*)d_ws;
    float* xcur = (float*)ws;                       ws += (size_t)NROW * D_  * 4;  // fp32 residual stream
    __hip_bfloat16* lnb = (__hip_bfloat16*)ws;      ws += (size_t)NROW * D_  * 2;  // LN output (bf16 A-operand)
    float* xg7  = (float*)ws;                       ws += (size_t)S_ * 4096  * 4;  // gate proj fp32 [s][4][8][64][2]
    __hip_bfloat16* hb  = (__hip_bfloat16*)ws;      ws += (size_t)NROW * H_  * 2;  // LSTM h (bf16 A-operand)
    __hip_bfloat16* f1  = (__hip_bfloat16*)ws;      ws += (size_t)NROW * DI_ * 2;  // FFN hidden (bf16 A-operand)
    __hip_bfloat16* wihb = (__hip_bfloat16*)ws;     ws += (size_t)L_ * G4H * D_ * 2;
    __hip_bfloat16* wfcb = (__hip_bfloat16*)ws;     ws += (size_t)L_ * D_ * H_ * 2;
    __hip_bfloat16* w1b  = (__hip_bfloat16*)ws;     ws += (size_t)L_ * DI_ * D_ * 2;
    __hip_bfloat16* w2b  = (__hip_bfloat16*)ws;     ws += (size_t)L_ * D_ * DI_ * 2;
    __hip_bfloat16* whf  = (__hip_bfloat16*)ws;     ws += (size_t)L_ * 16384 * 2;  // Whh A-frag bf16

    // one-time (per launch) weight conversions to bf16
    {
        int n4;
        n4 = L_ * G4H * D_ / 4;
        w2bf_kernel<<<(n4 + 255) / 256, 256, 0, stream>>>(wih, wihb, n4);
        n4 = L_ * D_ * H_ / 4;
        w2bf_kernel<<<(n4 + 255) / 256, 256, 0, stream>>>(wfc, wfcb, n4);
        n4 = L_ * DI_ * D_ / 4;
        w2bf_kernel<<<(n4 + 255) / 256, 256, 0, stream>>>(w1, w1b, n4);
        n4 = L_ * D_ * DI_ / 4;
        w2bf_kernel<<<(n4 + 255) / 256, 256, 0, stream>>>(w2, w2b, n4);
        whh_frag_kernel<<<(L_ * 16384) / 256, 256, 0, stream>>>(whh, whf);
    }

    hipMemcpyAsync(xcur, src, (size_t)NROW * D_ * sizeof(float),
                   hipMemcpyDeviceToDevice, stream);

    for (int l = 0; l < L_; l++) {
        // --- janossy layer ---
        ln_kernel<<<NROW, 256, 0, stream>>>(xcur, ln1_g + (size_t)l * D_,
                                            ln1_b + (size_t)l * D_, lnb);
        mfma_gemm<0, 0, 0, 2><<<dim3(G4H / 64, NROW / 64), 256, 0, stream>>>(
            lnb, wihb + (size_t)l * G4H * D_, nullptr, nullptr, xg7, NROW, G4H, D_);
        lstm_v5_kernel<<<dim3(S_, 2), 256, 0, stream>>>(
            xg7, whf + (size_t)l * 16384, hb);
        mfma_gemm<0, 0, 1, 0><<<dim3(D_ / 64, NROW / 64), 256, 0, stream>>>(
            hb, wfcb + (size_t)l * D_ * H_, nullptr, xcur, xcur, NROW, D_, H_);
        // --- FFN ---
        ln_kernel<<<NROW, 256, 0, stream>>>(xcur, ln2_g + (size_t)l * D_,
                                            ln2_b + (size_t)l * D_, lnb);
        mfma_gemm<1, 1, 0, 1><<<dim3(DI_ / 64, NROW / 64), 256, 0, stream>>>(
            lnb, w1b + (size_t)l * DI_ * D_, b1 + (size_t)l * DI_, nullptr, f1, NROW, DI_, D_);
        mfma_gemm<1, 0, 1, 0><<<dim3(D_ / 64, NROW / 64), 256, 0, stream>>>(
            f1, w2b + (size_t)l * D_ * DI_, b2 + (size_t)l * D_, xcur, xcur, NROW, D_, DI_);
    }
    final_kernel<<<NROW, 256, 0, stream>>>(xcur, lnf_g, lnf_b, wprj, out);
}